// Round 4
// baseline (296.228 us; speedup 1.0000x reference)
//
#include <hip/hip_runtime.h>

#define F1 64
#define F2 32
#define FIN 13
#define SCAN_B 256

// ---------- in-degree histogram (int atomics, L2-resident) ----------
__global__ void k_degree(const int* __restrict__ dst, int* __restrict__ indeg, int E) {
    int e = blockIdx.x * blockDim.x + threadIdx.x;
    if (e < E) atomicAdd(&indeg[dst[e]], 1);
}

// ---------- scan stage 1: per-block sums ----------
__global__ void k_scan1(const int* __restrict__ indeg, int* __restrict__ bsum, int N) {
    __shared__ int s[SCAN_B];
    int t = threadIdx.x;
    int i = blockIdx.x * SCAN_B + t;
    s[t] = (i < N) ? indeg[i] : 0;
    __syncthreads();
    for (int off = SCAN_B / 2; off > 0; off >>= 1) {
        if (t < off) s[t] += s[t + off];
        __syncthreads();
    }
    if (t == 0) bsum[blockIdx.x] = s[0];
}

// ---------- scan stage 2: exclusive scan of block sums (1 block, 512 thr) ----------
__global__ void k_scan2(int* __restrict__ bsum, int NB) {
    __shared__ int s[512];
    int t = threadIdx.x;
    int v = (t < NB) ? bsum[t] : 0;
    s[t] = v;
    __syncthreads();
    for (int off = 1; off < 512; off <<= 1) {
        int a = (t >= off) ? s[t - off] : 0;
        __syncthreads();
        s[t] += a;
        __syncthreads();
    }
    if (t < NB) bsum[t] = s[t] - v;   // exclusive
}

// ---------- scan stage 3: rowstart/cursor; dinv = rsqrt(deg+1) ----------
__global__ void k_scan3(const int* __restrict__ indeg, const int* __restrict__ bsum,
                        int* __restrict__ rowstart, int* __restrict__ cursor,
                        float* __restrict__ dinv, int N) {
    __shared__ int s[SCAN_B];
    int t = threadIdx.x;
    int i = blockIdx.x * SCAN_B + t;
    int v = (i < N) ? indeg[i] : 0;
    s[t] = v;
    __syncthreads();
    for (int off = 1; off < SCAN_B; off <<= 1) {
        int a = (t >= off) ? s[t - off] : 0;
        __syncthreads();
        s[t] += a;
        __syncthreads();
    }
    if (i < N) {
        int excl = bsum[blockIdx.x] + s[t] - v;
        rowstart[i] = excl;
        cursor[i] = excl;
        dinv[i] = rsqrtf((float)(v + 1));
    }
}

// ---------- CSR fill: csr[cursor[dst]++] = src via atomicExch (TCC-side write) ----------
__global__ void k_fill_csr(const int* __restrict__ src, const int* __restrict__ dst,
                           int* __restrict__ cursor, int* __restrict__ csr, int E) {
    int e = blockIdx.x * blockDim.x + threadIdx.x;
    if (e < E) {
        int d = dst[e];
        int pos = atomicAdd(&cursor[d], 1);
        atomicExch(&csr[pos], src[e]);   // atomic executes at L2 -> no 64B store-miss burst
    }
}

// ---------- xn[v][0..15] = x[v][c]*dinv[v] (c<13), 0 pad ----------
__global__ void k_xn(const float* __restrict__ x, const float* __restrict__ dinv,
                     float* __restrict__ xn, int N) {
    int i = blockIdx.x * blockDim.x + threadIdx.x;
    if (i >= N * 16) return;
    int v = i >> 4, c = i & 15;
    xn[i] = (c < FIN) ? x[(size_t)v * FIN + c] * dinv[v] : 0.f;
}

// ---------- fused layer1 agg + W1 transform + relu + W2 transform ----------
// 256 thr, 64 nodes/block.
// A: gather-agg xn (float4 lane per node quarter) -> sagg[64][16] (incl dinv scale)
// B: h[64][64] = relu(sagg @ W1 + b1)   (in LDS)
// C: y2[v][c] = (h @ W2)[c] * dinv[v]   (global, coalesced)
__global__ void k_agg1t(const float4* __restrict__ xn, const int* __restrict__ rowstart,
                        const int* __restrict__ indeg, const float* __restrict__ dinv,
                        const int* __restrict__ csr, const float* __restrict__ W1,
                        const float* __restrict__ b1, const float* __restrict__ W2,
                        float* __restrict__ y2, int N) {
    __shared__ float sW1[FIN * F1];
    __shared__ float sb1[F1];
    __shared__ float sW2[F1 * F2];
    __shared__ float sagg[64][16];
    __shared__ float sh[64][F1];
    int tid = threadIdx.x;
    for (int i = tid; i < FIN * F1; i += 256) sW1[i] = W1[i];
    for (int i = tid; i < F1 * F2; i += 256) sW2[i] = W2[i];
    if (tid < F1) sb1[tid] = b1[tid];
    int ln = tid >> 2;      // local node 0..63
    int l = tid & 3;        // float4 lane
    int v = blockIdx.x * 64 + ln;
    if (v < N) {
        int st = rowstart[v];
        int dg = indeg[v];
        float4 acc = xn[(size_t)v * 4 + l];   // self term (xn has one dinv)
        for (int e = 0; e < dg; ++e) {
            int s = csr[st + e];
            float4 u = xn[(size_t)s * 4 + l];
            acc.x += u.x; acc.y += u.y; acc.z += u.z; acc.w += u.w;
        }
        float dv = dinv[v];
        sagg[ln][l * 4 + 0] = acc.x * dv;
        sagg[ln][l * 4 + 1] = acc.y * dv;
        sagg[ln][l * 4 + 2] = acc.z * dv;
        sagg[ln][l * 4 + 3] = acc.w * dv;
    }
    __syncthreads();
    // B: h = relu(sagg @ W1 + b1)
    {
        int col = tid & 63;
        int sub = tid >> 6;     // 0..3
        int base = blockIdx.x * 64;
        for (int nn = sub; nn < 64; nn += 4) {
            if (base + nn >= N) break;
            float acc = sb1[col];
#pragma unroll
            for (int k = 0; k < FIN; ++k) acc += sagg[nn][k] * sW1[k * F1 + col];
            sh[nn][col] = fmaxf(acc, 0.f);
        }
    }
    __syncthreads();
    // C: y2 = (h @ W2) * dinv
    {
        int ng = tid >> 5;      // 0..7
        int c = tid & 31;
        int base = blockIdx.x * 64;
        for (int nn = ng; nn < 64; nn += 8) {
            int v2 = base + nn;
            if (v2 >= N) break;
            float acc = 0.f;
#pragma unroll
            for (int k = 0; k < F1; ++k) acc += sh[nn][k] * sW2[k * F2 + c];
            y2[(size_t)v2 * F2 + c] = acc * dinv[v2];
        }
    }
}

// ---------- layer2 aggregate: out2 = dinv*(y2[self] + sum y2[src]) + b2 ----------
__global__ void k_agg2(const float4* __restrict__ y2, const int* __restrict__ rowstart,
                       const int* __restrict__ indeg, const float* __restrict__ dinv,
                       const int* __restrict__ csr, const float* __restrict__ b2,
                       float4* __restrict__ out2, int N) {
    int tid = threadIdx.x;
    int ln = tid >> 3;      // 0..31
    int l = tid & 7;
    int v = blockIdx.x * 32 + ln;
    if (v >= N) return;
    int st = rowstart[v];
    int dg = indeg[v];
    float4 acc = y2[(size_t)v * 8 + l];
    for (int e = 0; e < dg; ++e) {
        int s = csr[st + e];
        float4 u = y2[(size_t)s * 8 + l];
        acc.x += u.x; acc.y += u.y; acc.z += u.z; acc.w += u.w;
    }
    float dv = dinv[v];
    float4 bb = ((const float4*)b2)[l];
    float4 o;
    o.x = acc.x * dv + bb.x;
    o.y = acc.y * dv + bb.y;
    o.z = acc.z * dv + bb.z;
    o.w = acc.w * dv + bb.w;
    out2[(size_t)v * 8 + l] = o;
}

// ---------- graph boundaries: gstart[g] = lower_bound(batch, g) ----------
__global__ void k_gstart(const int* __restrict__ batch, int* __restrict__ gstart,
                         int N, int G) {
    int g = blockIdx.x * blockDim.x + threadIdx.x;
    if (g > G) return;
    int lo = 0, hi = N;
    while (lo < hi) {
        int mid = (lo + hi) >> 1;
        if (batch[mid] < g) lo = mid + 1; else hi = mid;
    }
    gstart[g] = lo;
}

// ---------- fused mean-pool + MLP: one block per graph, no atomics ----------
__global__ void k_poolmlp(const float* __restrict__ out2, const int* __restrict__ gstart,
                          const float* __restrict__ fc1w, const float* __restrict__ fc1b,
                          const float* __restrict__ fc2w, const float* __restrict__ fc2b,
                          float* __restrict__ out, int G) {
    __shared__ float sW1[F2 * F2];
    __shared__ float sW2[F2 * F2];
    __shared__ float part[8][F2];
    __shared__ float gvec[F2];
    __shared__ float h1[F2];
    int tid = threadIdx.x;
    for (int i = tid; i < F2 * F2; i += 256) {
        sW1[i] = fc1w[i];
        sW2[i] = fc2w[i];
    }
    int g = blockIdx.x;
    int st = gstart[g], en = gstart[g + 1];
    int r = tid >> 5, c = tid & 31;
    float acc = 0.f;
    for (int v = st + r; v < en; v += 8) acc += out2[(size_t)v * F2 + c];
    part[r][c] = acc;
    __syncthreads();
    if (tid < F2) {
        float s = 0.f;
#pragma unroll
        for (int i = 0; i < 8; ++i) s += part[i][tid];
        float cnt = (float)(en - st);
        gvec[tid] = s / fmaxf(cnt, 1.0f);
    }
    __syncthreads();
    if (tid < F2) {
        float a = fc1b[tid];
#pragma unroll
        for (int k = 0; k < F2; ++k) a += gvec[k] * sW1[k * F2 + tid];
        h1[tid] = fmaxf(a, 0.f);
    }
    __syncthreads();
    if (tid < F2) {
        float a = fc2b[tid];
#pragma unroll
        for (int k = 0; k < F2; ++k) a += h1[k] * sW2[k * F2 + tid];
        out[(size_t)g * F2 + tid] = a;
    }
}

extern "C" void kernel_launch(void* const* d_in, const int* in_sizes, int n_in,
                              void* d_out, int out_size, void* d_ws, size_t ws_size,
                              hipStream_t stream) {
    const float* x    = (const float*)d_in[0];
    const int*   ei   = (const int*)d_in[1];
    const int*   batch= (const int*)d_in[2];
    const float* W1   = (const float*)d_in[3];
    const float* b1   = (const float*)d_in[4];
    const float* W2   = (const float*)d_in[5];
    const float* b2   = (const float*)d_in[6];
    const float* fc1w = (const float*)d_in[7];
    const float* fc1b = (const float*)d_in[8];
    const float* fc2w = (const float*)d_in[9];
    const float* fc2b = (const float*)d_in[10];
    float* out = (float*)d_out;

    const int N = in_sizes[0] / FIN;       // 100000
    const int E = in_sizes[1] / 2;         // 1250000
    const int G = out_size / F2;           // 512
    const int* src = ei;
    const int* dst = ei + E;
    const int NB = (N + SCAN_B - 1) / SCAN_B;   // 391

    // ---- workspace layout (4-byte units) ----
    int* wsi = (int*)d_ws;
    int* indeg    = wsi;                 // N
    int* rowstart = indeg + N;           // N
    int* cursor   = rowstart + N;        // N
    int* bsum     = cursor + N;          // 512
    int* gstart   = bsum + 512;          // G+1
    int* csr      = gstart + (G + 1);    // E
    size_t ioff = (size_t)(3 * N + 512 + G + 1) + E;
    ioff = (ioff + 3) & ~(size_t)3;      // 16B align for float4
    float* dinv   = (float*)(wsi + ioff);            // N
    size_t nal = (size_t)((N + 3) & ~3);
    float* xn     = dinv + nal;                      // N*16
    float* y2     = xn + (size_t)N * 16;             // N*32
    float* out2   = y2 + (size_t)N * F2;             // N*32

    const int B = 256;
    hipMemsetAsync(indeg, 0, (size_t)N * sizeof(int), stream);

    hipLaunchKernelGGL(k_degree, dim3((E + B - 1) / B), dim3(B), 0, stream, dst, indeg, E);
    hipLaunchKernelGGL(k_scan1, dim3(NB), dim3(SCAN_B), 0, stream, indeg, bsum, N);
    hipLaunchKernelGGL(k_scan2, dim3(1), dim3(512), 0, stream, bsum, NB);
    hipLaunchKernelGGL(k_scan3, dim3(NB), dim3(SCAN_B), 0, stream,
                       indeg, bsum, rowstart, cursor, dinv, N);
    hipLaunchKernelGGL(k_fill_csr, dim3((E + B - 1) / B), dim3(B), 0, stream,
                       src, dst, cursor, csr, E);
    hipLaunchKernelGGL(k_xn, dim3(((long)N * 16 + B - 1) / B), dim3(B), 0, stream,
                       x, dinv, xn, N);
    hipLaunchKernelGGL(k_agg1t, dim3((N + 63) / 64), dim3(B), 0, stream,
                       (const float4*)xn, rowstart, indeg, dinv, csr, W1, b1, W2, y2, N);
    hipLaunchKernelGGL(k_agg2, dim3((N + 31) / 32), dim3(B), 0, stream,
                       (const float4*)y2, rowstart, indeg, dinv, csr, b2,
                       (float4*)out2, N);
    hipLaunchKernelGGL(k_gstart, dim3((G + 1 + B - 1) / B), dim3(B), 0, stream,
                       batch, gstart, N, G);
    hipLaunchKernelGGL(k_poolmlp, dim3(G), dim3(B), 0, stream,
                       out2, gstart, fc1w, fc1b, fc2w, fc2b, out, G);
}